// Round 7
// baseline (63.962 us; speedup 1.0000x reference)
//
#include <hip/hip_runtime.h>
#include <hip/hip_bf16.h>

#define CC   256
#define HH   200
#define WW   200
#define KK   1024
#define OH_  14
#define OW_  14
#define OHW  196         // 14*14
#define HW   (HH * WW)   // 40000
#define NG   8           // channel groups (one per XCD)
#define GCH  32          // channels per group
#define ROWB (GCH * 2)   // 64 bytes per (group,position) row

static __device__ __forceinline__ float lo_bf(unsigned int u) {
  union { unsigned int i; float f; } x; x.i = u << 16; return x.f;
}
static __device__ __forceinline__ float hi_bf(unsigned int u) {
  union { unsigned int i; float f; } x; x.i = u & 0xFFFF0000u; return x.f;
}

// ---- transpose+convert: img [C,H*W] f32 -> ws [NG][HW][GCH] bf16 ----------
// Group-major: each XCD's 32-channel slice is a contiguous 2.56 MB block,
// one position = one 64B line (L2-resident, zero line waste).
__global__ __launch_bounds__(256) void transpose_bf16_kernel(
    const float* __restrict__ img, unsigned short* __restrict__ ws) {
  __shared__ float tile[64][66];  // pad 66: f2 writes aligned+free, reads 2-way
  const int hw0 = blockIdx.x * 64;
  const int c0  = blockIdx.y * 64;   // spans groups 2*by and 2*by+1
  // load phase: 64ch x 64hw as float4 (4 instrs/thread)
#pragma unroll
  for (int j = 0; j < 4; ++j) {
    const int idx = j * 256 + threadIdx.x;
    const int c   = idx >> 4;        // 0..63
    const int x   = (idx & 15) * 4;  // 0..60
    const float4 v = *(const float4*)&img[(size_t)(c0 + c) * HW + hw0 + x];
    *(float2*)&tile[c][x]     = make_float2(v.x, v.y);
    *(float2*)&tile[c][x + 2] = make_float2(v.z, v.w);
  }
  __syncthreads();
  // write phase: l over [2 groups][64 rows][8 ch-quads]; wave = 512B contig
#pragma unroll
  for (int j = 0; j < 4; ++j) {
    const int l   = j * 256 + threadIdx.x;
    const int gg  = l >> 9;          // 0..1 group-local
    const int rem = l & 511;
    const int r   = rem >> 3;        // 0..63 hw row
    const int q   = rem & 7;         // ch quad
    const int cl  = gg * 32 + 4 * q; // tile row base
    const float a = tile[cl + 0][r];
    const float b = tile[cl + 1][r];
    const float c = tile[cl + 2][r];
    const float d = tile[cl + 3][r];
    const __hip_bfloat16 ba = __float2bfloat16(a);  // RNE
    const __hip_bfloat16 bb = __float2bfloat16(b);
    const __hip_bfloat16 bc = __float2bfloat16(c);
    const __hip_bfloat16 bd = __float2bfloat16(d);
    const unsigned int lo = (unsigned int)*(const unsigned short*)&ba |
                            ((unsigned int)*(const unsigned short*)&bb << 16);
    const unsigned int hi = (unsigned int)*(const unsigned short*)&bc |
                            ((unsigned int)*(const unsigned short*)&bd << 16);
    const int G = (c0 >> 5) + gg;    // absolute group
    *(uint2*)&ws[(size_t)G * HW * GCH + (size_t)(hw0 + r) * GCH + 4 * q] =
        make_uint2(lo, hi);
  }
}

// ---------- per-box sample table (row-byte-offset indices, folded wts) ----
__device__ __forceinline__ void precompute_pos(
    const float* __restrict__ boxes, int k, int tid,
    int4* sidx, float4* sw, int idx_scale) {
  if (tid < OHW) {
    const float xmin = boxes[k * 4 + 0];
    const float ymin = boxes[k * 4 + 1];
    const float xmax = boxes[k * 4 + 2];
    const float ymax = boxes[k * 4 + 3];
    const float a11 = (xmax - xmin) / 14.0f;
    const float a22 = (ymax - ymin) / 14.0f;
    const int ow = tid % OW_;
    const int oh = tid / OW_;
    // replicate reference FP sequence exactly
    const float xi = a11 * (float)ow + xmin;
    const float yi = a22 * (float)oh + ymin;
    const float gx = (xi - 100.0f) / 200.0f * 2.0f;
    const float gy = (yi - 100.0f) / 200.0f * 2.0f;
    const float x  = ((gx + 1.0f) * 200.0f - 1.0f) * 0.5f;
    const float y  = ((gy + 1.0f) * 200.0f - 1.0f) * 0.5f;
    const float fx0 = floorf(x);
    const float fy0 = floorf(y);
    const float wx = x - fx0;
    const float wy = y - fy0;
    const int x0 = (int)fx0, y0 = (int)fy0;
    const int x1 = x0 + 1,   y1 = y0 + 1;
    const bool vx0 = (x0 >= 0) & (x0 < WW);
    const bool vx1 = (x1 >= 0) & (x1 < WW);
    const bool vy0 = (y0 >= 0) & (y0 < HH);
    const bool vy1 = (y1 >= 0) & (y1 < HH);
    const int cx0 = min(max(x0, 0), WW - 1);
    const int cx1 = min(max(x1, 0), WW - 1);
    const int cy0 = min(max(y0, 0), HH - 1);
    const int cy1 = min(max(y1, 0), HH - 1);
    sidx[tid] = make_int4((cy0 * WW + cx0) * idx_scale, (cy0 * WW + cx1) * idx_scale,
                          (cy1 * WW + cx0) * idx_scale, (cy1 * WW + cx1) * idx_scale);
    sw[tid] = make_float4((1.0f - wy) * (1.0f - wx) * (float)(vy0 && vx0),
                          (1.0f - wy) * wx          * (float)(vy0 && vx1),
                          wy          * (1.0f - wx) * (float)(vy1 && vx0),
                          wy          * wx          * (float)(vy1 && vx1));
  }
}

// ---------- gather: ws [NG][HW][GCH] bf16 -> out [K,C,OH,OW] f32 ----------
// T14 async-stage pipeline: 3 chunks {64,64,68}; next chunk's register
// loads are issued before the store phase, so L2 latency hides under the
// HBM write stream. blockIdx.x = k*8 + g -> XCD-pinned 2.56 MB L2 slice.
__global__ __launch_bounds__(256, 6) void crop_resize_bf16(
    const unsigned short* __restrict__ ws, const float* __restrict__ boxes,
    float* __restrict__ out) {
  __shared__ int4   sidx[OHW];
  __shared__ float4 sw[OHW];
  __shared__ float  tile[68][33];  // 9.0 KB; gather writes 2-way (free)

  const int b   = blockIdx.x;
  const int g   = b & 7;
  const int k   = b >> 3;
  const int tid = threadIdx.x;
  precompute_pos(boxes, k, tid, sidx, sw, ROWB);  // row byte offsets (row*64)
  __syncthreads();

  const int cp = tid & 15;   // channel pair 0..15
  const int po = tid >> 4;   // position offset 0..15
  const char* wsb = (const char*)ws + ((size_t)g * HW * GCH * 2 + cp * 4);
  char* ob = (char*)out + (((size_t)k * CC + g * GCH) * OHW) * 4;

  unsigned int u[5][4];  // in-flight corner dwords (static-indexed only)

#define ISSUE4(slot_, p_)                                                     \
  {                                                                           \
    const int4 id = sidx[p_];                                                 \
    u[slot_][0] = *(const unsigned int*)(wsb + id.x);                         \
    u[slot_][1] = *(const unsigned int*)(wsb + id.y);                         \
    u[slot_][2] = *(const unsigned int*)(wsb + id.z);                         \
    u[slot_][3] = *(const unsigned int*)(wsb + id.w);                         \
  }
#define CONSUME(slot_, p_, row_)                                              \
  {                                                                           \
    const float4 wt = sw[p_];                                                 \
    tile[row_][2 * cp]     = wt.x * lo_bf(u[slot_][0]) +                      \
                             wt.y * lo_bf(u[slot_][1]) +                      \
                             wt.z * lo_bf(u[slot_][2]) +                      \
                             wt.w * lo_bf(u[slot_][3]);                       \
    tile[row_][2 * cp + 1] = wt.x * hi_bf(u[slot_][0]) +                      \
                             wt.y * hi_bf(u[slot_][1]) +                      \
                             wt.z * hi_bf(u[slot_][2]) +                      \
                             wt.w * hi_bf(u[slot_][3]);                       \
  }
#define STORE(cb_, nf4_)                                                      \
  for (int j = tid; j < GCH * (nf4_); j += 256) {                             \
    const int cc = j / (nf4_);                                                \
    const int q  = j - cc * (nf4_);                                           \
    const float4 v = make_float4(tile[4 * q][cc],     tile[4 * q + 1][cc],    \
                                 tile[4 * q + 2][cc], tile[4 * q + 3][cc]);   \
    *(float4*)(ob + (size_t)cc * (OHW * 4) + (cb_) * 4 + q * 16) = v;         \
  }

  // prologue: issue chunk 0 (positions 0..63)
#pragma unroll
  for (int i = 0; i < 4; ++i) ISSUE4(i, po + 16 * i);

  // ---- chunk 0 ----
#pragma unroll
  for (int i = 0; i < 4; ++i) CONSUME(i, po + 16 * i, po + 16 * i);
#pragma unroll
  for (int i = 0; i < 4; ++i) ISSUE4(i, 64 + po + 16 * i);  // chunk 1 in flight
  __syncthreads();
  STORE(0, 16)
  __syncthreads();

  // ---- chunk 1 ----
#pragma unroll
  for (int i = 0; i < 4; ++i) CONSUME(i, 64 + po + 16 * i, po + 16 * i);
#pragma unroll
  for (int i = 0; i < 4; ++i) ISSUE4(i, 128 + po + 16 * i);  // chunk 2 in flight
  if (po < 4) ISSUE4(4, 192 + po);                           // chunk 2 tail
  __syncthreads();
  STORE(64, 16)
  __syncthreads();

  // ---- chunk 2 (68 positions) ----
#pragma unroll
  for (int i = 0; i < 4; ++i) CONSUME(i, 128 + po + 16 * i, po + 16 * i);
  if (po < 4) CONSUME(4, 192 + po, 64 + po);
  __syncthreads();
  STORE(128, 17)

#undef ISSUE4
#undef CONSUME
#undef STORE
}

// ---------- fallback direct kernel (ws too small) ----------
#define NCHUNK 32
#define CPB    (CC / NCHUNK)  // 8
__global__ __launch_bounds__(256) void crop_resize_direct(
    const float* __restrict__ img, const float* __restrict__ boxes,
    float* __restrict__ out) {
  __shared__ int4   sidx[OHW];
  __shared__ float4 sw[OHW];
  const int k      = blockIdx.x;
  const int cchunk = blockIdx.y;
  const int tid    = threadIdx.x;
  precompute_pos(boxes, k, tid, sidx, sw, 1);
  __syncthreads();

  const int c0 = cchunk * CPB;
  const int total = CPB * OHW;
  float* outk = out + (size_t)k * CC * OHW + (size_t)c0 * OHW;
  const float* imgc0 = img + (size_t)c0 * HW;

#pragma unroll 4
  for (int i = tid; i < total; i += 256) {
    const int c   = i / OHW;
    const int pos = i - c * OHW;
    const int4   id = sidx[pos];
    const float4 wd = sw[pos];
    const float* p  = imgc0 + c * HW;
    const float v = wd.x * p[id.x] + wd.y * p[id.y] +
                    wd.z * p[id.z] + wd.w * p[id.w];
    outk[i] = v;
  }
}

extern "C" void kernel_launch(void* const* d_in, const int* in_sizes, int n_in,
                              void* d_out, int out_size, void* d_ws, size_t ws_size,
                              hipStream_t stream) {
  const float* img   = (const float*)d_in[0];
  const float* boxes = (const float*)d_in[1];
  float* out = (float*)d_out;
  const size_t need = (size_t)HW * CC * sizeof(unsigned short);  // 20.48 MB
  if (ws_size >= need) {
    unsigned short* wsimg = (unsigned short*)d_ws;
    hipLaunchKernelGGL(transpose_bf16_kernel, dim3(HW / 64, CC / 64), dim3(256),
                       0, stream, img, wsimg);
    hipLaunchKernelGGL(crop_resize_bf16, dim3(KK * NG), dim3(256), 0, stream,
                       wsimg, boxes, out);
  } else {
    hipLaunchKernelGGL(crop_resize_direct, dim3(KK, NCHUNK), dim3(256), 0,
                       stream, img, boxes, out);
  }
}